// Round 2
// baseline (477.032 us; speedup 1.0000x reference)
//
#include <hip/hip_runtime.h>

// Problem: B=65536, S=512, N=514
// Q = M0*...*M513, Mi = I - 2 v_i v_i^T/(v_i^T v_i + eps)
// Compact WY: Q = I - U V^T, U = V R^{-1}, R = striu(G) + diag((G_ii+eps)/2)
// out = x Q^T = x (I - V U^T) = x @ QT,  QT[t][s] = d_ts - sum_i v[i][t] U[s][i]
// We store QTT[s][t] = QT[t][s] (fp16) as B^T operand for the MFMA GEMM.

#define LDG 520
#define GROWS 528
#define LDU 520
#define NHH 514
#define SDIM 512
#define EPS_HH 1e-16f

typedef float f32x4 __attribute__((ext_vector_type(4)));
typedef __fp16 h16x2 __attribute__((ext_vector_type(2)));
typedef __fp16 h16x8 __attribute__((ext_vector_type(8)));

__device__ __forceinline__ void gl_lds16(const void* g, void* l) {
  __builtin_amdgcn_global_load_lds((const __attribute__((address_space(1))) void*)g,
                                   (__attribute__((address_space(3))) void*)l, 16, 0, 0);
}

// ---------------- Gram: G[i][j] = sum_s v[i][s] v[j][s] ----------------
__global__ __launch_bounds__(256) void gram_k(const float* __restrict__ v,
                                              float* __restrict__ G) {
  __shared__ float As[32][33];
  __shared__ float Bs[32][33];
  const int t = threadIdx.x;
  const int i0 = blockIdx.y * 32, j0 = blockIdx.x * 32;
  const int tx = t & 15, ty = t >> 4;
  float acc00 = 0.f, acc01 = 0.f, acc10 = 0.f, acc11 = 0.f;
  for (int kb = 0; kb < SDIM; kb += 32) {
    __syncthreads();
#pragma unroll
    for (int q = 0; q < 4; q++) {
      int idx = q * 256 + t;
      int r = idx >> 5, c = idx & 31;
      As[r][c] = (i0 + r < NHH) ? v[(size_t)(i0 + r) * SDIM + kb + c] : 0.f;
      Bs[r][c] = (j0 + r < NHH) ? v[(size_t)(j0 + r) * SDIM + kb + c] : 0.f;
    }
    __syncthreads();
#pragma unroll
    for (int kk = 0; kk < 32; kk++) {
      float a0 = As[ty * 2][kk], a1 = As[ty * 2 + 1][kk];
      float b0 = Bs[tx * 2][kk], b1 = Bs[tx * 2 + 1][kk];
      acc00 = fmaf(a0, b0, acc00);
      acc01 = fmaf(a0, b1, acc01);
      acc10 = fmaf(a1, b0, acc10);
      acc11 = fmaf(a1, b1, acc11);
    }
  }
  int row0 = i0 + ty * 2, col0 = j0 + tx * 2;
  if (row0 < NHH) {
    if (col0 < LDG) G[(size_t)row0 * LDG + col0] = acc00;
    if (col0 + 1 < LDG) G[(size_t)row0 * LDG + col0 + 1] = acc01;
  }
  if (row0 + 1 < NHH) {
    if (col0 < LDG) G[(size_t)(row0 + 1) * LDG + col0] = acc10;
    if (col0 + 1 < LDG) G[(size_t)(row0 + 1) * LDG + col0 + 1] = acc11;
  }
}

// ---------------- Solve: U R = V^T-rows, one wave per row s ----------------
__device__ __forceinline__ float sel9(const float (&a)[9], int c) {
  switch (c) {
    case 0: return a[0];
    case 1: return a[1];
    case 2: return a[2];
    case 3: return a[3];
    case 4: return a[4];
    case 5: return a[5];
    case 6: return a[6];
    case 7: return a[7];
    default: return a[8];
  }
}

__global__ __launch_bounds__(256) void solve_k(const float* __restrict__ v,
                                               const float* __restrict__ G,
                                               float* __restrict__ U) {
  const int lane = threadIdx.x & 63;
  const int s = blockIdx.x * 4 + (threadIdx.x >> 6);
  float W[9];
  float binv[9];
#pragma unroll
  for (int k = 0; k < 9; k++) {
    int j = k * 64 + lane;
    W[k] = (j < NHH) ? v[(size_t)j * SDIM + s] : 0.f;
    binv[k] = (j < NHH) ? (2.0f / (G[(size_t)j * LDG + j] + EPS_HH)) : 0.f;
  }
  float* Urow = U + (size_t)s * LDU;
  float g[8][9];
#pragma unroll
  for (int p = 0; p < 7; p++) {
    const float* gp = G + (size_t)p * LDG + lane;
#pragma unroll
    for (int k = 0; k < 9; k++) g[p][k] = gp[k * 64];
  }
  float usave = 0.f;

#define HH_STEP(I, SLOT, PSLOT, DO_PF)                                     \
  do {                                                                     \
    const int i_ = (I);                                                    \
    if (DO_PF) {                                                           \
      const float* gp_ = G + (size_t)(i_ + 7) * LDG + lane;                \
      _Pragma("unroll") for (int k = 0; k < 9; k++) g[PSLOT][k] =          \
          gp_[k * 64];                                                     \
    }                                                                      \
    const int c_ = i_ >> 6, sl_ = i_ & 63;                                 \
    float u_ = __shfl(sel9(W, c_) * sel9(binv, c_), sl_, 64);              \
    if (lane == sl_) usave = u_;                                           \
    _Pragma("unroll") for (int k = 0; k < 9; k++) W[k] =                   \
        fmaf(-u_, g[SLOT][k], W[k]);                                       \
    if (sl_ == 63) Urow[i_ - 63 + lane] = usave;                           \
  } while (0)

  for (int base = 0; base < 512; base += 8) {
    HH_STEP(base + 0, 0, 7, true);
    HH_STEP(base + 1, 1, 0, true);
    HH_STEP(base + 2, 2, 1, true);
    HH_STEP(base + 3, 3, 2, true);
    HH_STEP(base + 4, 4, 3, true);
    HH_STEP(base + 5, 5, 4, true);
    HH_STEP(base + 6, 6, 5, true);
    HH_STEP(base + 7, 7, 6, true);
  }
  HH_STEP(512, 0, 0, false);
  HH_STEP(513, 1, 0, false);
  if (lane < 2) Urow[512 + lane] = usave;
#undef HH_STEP
}

// ---------------- QTT[s][t] = delta - sum_i U[s][i] v[i][t]  (fp16) -------
__global__ __launch_bounds__(256) void qtt_k(const float* __restrict__ v,
                                             const float* __restrict__ U,
                                             __fp16* __restrict__ QTT) {
  __shared__ float As[32][33];
  __shared__ float Bs[32][33];
  const int t = threadIdx.x;
  const int s0 = blockIdx.y * 32, t0 = blockIdx.x * 32;
  const int tx = t & 15, ty = t >> 4;
  float acc00 = 0.f, acc01 = 0.f, acc10 = 0.f, acc11 = 0.f;
  for (int kb = 0; kb < NHH; kb += 32) {
    __syncthreads();
#pragma unroll
    for (int q = 0; q < 4; q++) {
      int idx = q * 256 + t;
      int r = idx >> 5, c = idx & 31;
      As[r][c] = (kb + c < NHH) ? U[(size_t)(s0 + r) * LDU + kb + c] : 0.f;
      Bs[r][c] = (kb + r < NHH) ? v[(size_t)(kb + r) * SDIM + t0 + c] : 0.f;
    }
    __syncthreads();
#pragma unroll
    for (int kk = 0; kk < 32; kk++) {
      float a0 = As[ty * 2][kk], a1 = As[ty * 2 + 1][kk];
      float b0 = Bs[kk][tx * 2], b1 = Bs[kk][tx * 2 + 1];
      acc00 = fmaf(a0, b0, acc00);
      acc01 = fmaf(a0, b1, acc01);
      acc10 = fmaf(a1, b0, acc10);
      acc11 = fmaf(a1, b1, acc11);
    }
  }
  int row0 = s0 + ty * 2, col0 = t0 + tx * 2;
  QTT[(size_t)row0 * SDIM + col0] =
      (__fp16)(((row0 == col0) ? 1.f : 0.f) - acc00);
  QTT[(size_t)row0 * SDIM + col0 + 1] =
      (__fp16)(((row0 == col0 + 1) ? 1.f : 0.f) - acc01);
  QTT[(size_t)(row0 + 1) * SDIM + col0] =
      (__fp16)(((row0 + 1 == col0) ? 1.f : 0.f) - acc10);
  QTT[(size_t)(row0 + 1) * SDIM + col0 + 1] =
      (__fp16)(((row0 + 1 == col0 + 1) ? 1.f : 0.f) - acc11);
}

// ---------------- Main GEMM: C[65536x512] = X(f32->f16) @ QTT^T ----------
__global__ __launch_bounds__(256) void gemm_k(const float* __restrict__ X,
                                              const __fp16* __restrict__ BT,
                                              float* __restrict__ C) {
  __shared__ __attribute__((aligned(16))) float As[128 * 32];
  __shared__ __attribute__((aligned(16))) __fp16 Bs[128 * 32];
  const int t = threadIdx.x;
  const int lane = t & 63, wave = t >> 6;
  const int m0 = blockIdx.y * 128, n0 = blockIdx.x * 128;
  const int wm = (wave >> 1) * 64, wn = (wave & 1) * 64;
  const int rr = lane & 15, kg = lane >> 4;
  const int wb = t & ~63;  // wave-uniform thread base

  f32x4 acc[4][4];
#pragma unroll
  for (int a = 0; a < 4; a++)
#pragma unroll
    for (int b = 0; b < 4; b++) acc[a][b] = (f32x4){0.f, 0.f, 0.f, 0.f};

  for (int k0 = 0; k0 < 512; k0 += 32) {
    __syncthreads();
    // A tile: 128x32 f32, 16 KB -> 4 issues of 16B/lane
#pragma unroll
    for (int q = 0; q < 4; q++) {
      int idx = q * 256 + t;
      int r = idx >> 3, c = (idx & 7) * 4;
      const float* gp = X + (size_t)(m0 + r) * 512 + k0 + c;
      gl_lds16(gp, (void*)&As[(size_t)(q * 256 + wb) * 4]);
    }
    // B tile: 128x32 f16, 8 KB -> 2 issues
#pragma unroll
    for (int q = 0; q < 2; q++) {
      int idx = q * 256 + t;
      int r = idx >> 2, c = (idx & 3) * 8;
      const __fp16* gp = BT + (size_t)(n0 + r) * 512 + k0 + c;
      gl_lds16(gp, (void*)&Bs[(size_t)(q * 256 + wb) * 8]);
    }
    asm volatile("s_waitcnt vmcnt(0)" ::: "memory");
    __syncthreads();

    h16x8 af[4], bf[4];
#pragma unroll
    for (int mi = 0; mi < 4; mi++) {
      const float* ap = &As[(size_t)(wm + mi * 16 + rr) * 32 + kg * 8];
      float4 lo = *(const float4*)ap;
      float4 hi = *(const float4*)(ap + 4);
      h16x2 p0 = __builtin_amdgcn_cvt_pkrtz(lo.x, lo.y);
      h16x2 p1 = __builtin_amdgcn_cvt_pkrtz(lo.z, lo.w);
      h16x2 p2 = __builtin_amdgcn_cvt_pkrtz(hi.x, hi.y);
      h16x2 p3 = __builtin_amdgcn_cvt_pkrtz(hi.z, hi.w);
      h16x8 a = {p0[0], p0[1], p1[0], p1[1], p2[0], p2[1], p3[0], p3[1]};
      af[mi] = a;
    }
#pragma unroll
    for (int ni = 0; ni < 4; ni++)
      bf[ni] = *(const h16x8*)&Bs[(size_t)(wn + ni * 16 + rr) * 32 + kg * 8];

#pragma unroll
    for (int mi = 0; mi < 4; mi++)
#pragma unroll
      for (int ni = 0; ni < 4; ni++)
        acc[mi][ni] =
            __builtin_amdgcn_mfma_f32_16x16x32_f16(af[mi], bf[ni], acc[mi][ni], 0, 0, 0);
  }

  const int rg = lane >> 4;
  float* Cb = C + (size_t)(m0 + wm) * 512 + n0 + wn;
#pragma unroll
  for (int mi = 0; mi < 4; mi++)
#pragma unroll
    for (int ni = 0; ni < 4; ni++)
#pragma unroll
      for (int r = 0; r < 4; r++)
        Cb[(size_t)(mi * 16 + rg * 4 + r) * 512 + ni * 16 + rr] =
            acc[mi][ni][r];
}

extern "C" void kernel_launch(void* const* d_in, const int* in_sizes, int n_in,
                              void* d_out, int out_size, void* d_ws, size_t ws_size,
                              hipStream_t stream) {
  const float* x = (const float*)d_in[0];        // [65536][512] f32
  const float* v = (const float*)d_in[1];        // [514][512] f32
  float* out = (float*)d_out;                    // [65536][512] f32

  char* w = (char*)d_ws;
  float* G = (float*)w;                                   // 528*520*4 = 1,098,240 B
  float* U = (float*)(w + (size_t)GROWS * LDG * 4);       // 512*520*4 = 1,064,960 B
  __fp16* QTT =
      (__fp16*)(w + (size_t)GROWS * LDG * 4 + (size_t)512 * LDU * 4);  // 512 KB

  gram_k<<<dim3(17, 17), 256, 0, stream>>>(v, G);
  solve_k<<<128, 256, 0, stream>>>(v, G, U);
  qtt_k<<<dim3(16, 16), 256, 0, stream>>>(v, U, QTT);
  gemm_k<<<dim3(4, 512), 256, 0, stream>>>(x, QTT, out);
}

// Round 3
// 368.355 us; speedup vs baseline: 1.2950x; 1.2950x over previous
//
#include <hip/hip_runtime.h>

// Problem: B=65536, S=512, N=514
// Q = M0*...*M513, Mi = I - 2 v_i v_i^T/(v_i^T v_i + eps)
// Compact WY: Q = I - U V^T, U = V R^{-1}, R = striu(G) + diag((G_ii+eps)/2)
// out = x Q^T = x (I - V U^T) = x @ QT,  QT[t][s] = d_ts - sum_i v[i][t] U[s][i]
// QTT[s][t] = QT[t][s] (fp16) is the B^T operand for the MFMA GEMM.

#define LDG 520
#define GROWS 528
#define LDU 520
#define NHH 514
#define SDIM 512
#define EPS_HH 1e-16f

typedef float f32x4 __attribute__((ext_vector_type(4)));
typedef __fp16 h16x2 __attribute__((ext_vector_type(2)));
typedef __fp16 h16x8 __attribute__((ext_vector_type(8)));

__device__ __forceinline__ void gl_lds16(const void* g, void* l) {
  __builtin_amdgcn_global_load_lds((const __attribute__((address_space(1))) void*)g,
                                   (__attribute__((address_space(3))) void*)l, 16, 0, 0);
}

// ---------------- Gram: G[i][j] = sum_s v[i][s] v[j][s] ----------------
__global__ __launch_bounds__(256) void gram_k(const float* __restrict__ v,
                                              float* __restrict__ G) {
  __shared__ float As[32][36];
  __shared__ float Bs[32][36];
  const int t = threadIdx.x;
  const int i0 = blockIdx.y * 32, j0 = blockIdx.x * 32;
  const int tx = t & 15, ty = t >> 4;
  const int r = t >> 3, c4 = (t & 7) * 4;
  float acc00 = 0.f, acc01 = 0.f, acc10 = 0.f, acc11 = 0.f;
  for (int kb = 0; kb < SDIM; kb += 32) {
    __syncthreads();
    float4 av = (i0 + r < NHH)
                    ? *(const float4*)(v + (size_t)(i0 + r) * SDIM + kb + c4)
                    : make_float4(0.f, 0.f, 0.f, 0.f);
    float4 bv = (j0 + r < NHH)
                    ? *(const float4*)(v + (size_t)(j0 + r) * SDIM + kb + c4)
                    : make_float4(0.f, 0.f, 0.f, 0.f);
    *(float4*)&As[r][c4] = av;
    *(float4*)&Bs[r][c4] = bv;
    __syncthreads();
#pragma unroll
    for (int kk = 0; kk < 32; kk++) {
      float a0 = As[ty * 2][kk], a1 = As[ty * 2 + 1][kk];
      float b0 = Bs[tx * 2][kk], b1 = Bs[tx * 2 + 1][kk];
      acc00 = fmaf(a0, b0, acc00);
      acc01 = fmaf(a0, b1, acc01);
      acc10 = fmaf(a1, b0, acc10);
      acc11 = fmaf(a1, b1, acc11);
    }
  }
  int row0 = i0 + ty * 2, col0 = j0 + tx * 2;
  if (row0 < NHH) {
    if (col0 < LDG) G[(size_t)row0 * LDG + col0] = acc00;
    if (col0 + 1 < LDG) G[(size_t)row0 * LDG + col0 + 1] = acc01;
  }
  if (row0 + 1 < NHH) {
    if (col0 < LDG) G[(size_t)(row0 + 1) * LDG + col0] = acc10;
    if (col0 + 1 < LDG) G[(size_t)(row0 + 1) * LDG + col0 + 1] = acc11;
  }
}

// ---------------- Solve: U R = V^T-rows, one wave per row s ----------------
// __launch_bounds__(256,1): grid is 512 waves on 256 CUs (2/CU), occupancy is
// grid-limited; give the register allocator the full budget so the 8-row G
// prefetch ring (72 VGPRs) stays in registers. (R2: default bounds capped at
// 64 VGPR -> full ring spilled to scratch -> 120 us.)
__global__ __launch_bounds__(256, 1) void solve_k(const float* __restrict__ v,
                                                  const float* __restrict__ G,
                                                  float* __restrict__ U) {
  const int lane = threadIdx.x & 63;
  const int s = blockIdx.x * 4 + (threadIdx.x >> 6);
  float W[9];
  float binv[9];
#pragma unroll
  for (int k = 0; k < 9; k++) {
    int j = k * 64 + lane;
    W[k] = (j < NHH) ? v[(size_t)j * SDIM + s] : 0.f;
    binv[k] = (j < NHH) ? (2.0f / (G[(size_t)j * LDG + j] + EPS_HH)) : 0.f;
  }
  float* Urow = U + (size_t)s * LDU;
  float g[8][9];
#pragma unroll
  for (int p = 0; p < 7; p++) {
    const float* gp = G + (size_t)p * LDG + lane;
#pragma unroll
    for (int k = 0; k < 9; k++) g[p][k] = gp[k * 64];
  }
  float usave = 0.f;

  // CI is a compile-time constant (c-loop unrolled) so W[CI]/binv[CI] are
  // direct register refs -- no select chain in the serial dependency path.
#define HH_STEP(I, CI, SLOT, PSLOT, DO_PF)                                 \
  do {                                                                     \
    const int i_ = (I);                                                    \
    if (DO_PF) {                                                           \
      const float* gp_ = G + (size_t)(i_ + 7) * LDG + lane;                \
      _Pragma("unroll") for (int k = 0; k < 9; k++) g[PSLOT][k] =          \
          gp_[k * 64];                                                     \
    }                                                                      \
    const int sl_ = i_ & 63;                                               \
    float u_ = __shfl(W[CI] * binv[CI], sl_, 64);                          \
    if (lane == sl_) usave = u_;                                           \
    _Pragma("unroll") for (int k = 0; k < 9; k++) W[k] =                   \
        fmaf(-u_, g[SLOT][k], W[k]);                                       \
    if (sl_ == 63) Urow[i_ - 63 + lane] = usave;                           \
  } while (0)

#pragma unroll
  for (int c = 0; c < 8; c++) {
    for (int q = 0; q < 8; q++) {
      const int base = c * 64 + q * 8;
      HH_STEP(base + 0, c, 0, 7, true);
      HH_STEP(base + 1, c, 1, 0, true);
      HH_STEP(base + 2, c, 2, 1, true);
      HH_STEP(base + 3, c, 3, 2, true);
      HH_STEP(base + 4, c, 4, 3, true);
      HH_STEP(base + 5, c, 5, 4, true);
      HH_STEP(base + 6, c, 6, 5, true);
      HH_STEP(base + 7, c, 7, 6, true);
    }
  }
  HH_STEP(512, 8, 0, 0, false);
  HH_STEP(513, 8, 1, 0, false);
  if (lane < 2) Urow[512 + lane] = usave;
#undef HH_STEP
}

// ---------------- QTT[s][t] = delta - sum_i U[s][i] v[i][t]  (fp16) -------
__global__ __launch_bounds__(256) void qtt_k(const float* __restrict__ v,
                                             const float* __restrict__ U,
                                             __fp16* __restrict__ QTT) {
  __shared__ float As[32][36];
  __shared__ float Bs[32][36];
  const int t = threadIdx.x;
  const int s0 = blockIdx.y * 32, t0 = blockIdx.x * 32;
  const int tx = t & 15, ty = t >> 4;
  const int r = t >> 3, c4 = (t & 7) * 4;
  float acc00 = 0.f, acc01 = 0.f, acc10 = 0.f, acc11 = 0.f;
  for (int kb = 0; kb < NHH; kb += 32) {
    __syncthreads();
    // U cols >=514 are garbage (finite) but multiply Bs rows that are zeroed.
    float4 av = *(const float4*)(U + (size_t)(s0 + r) * LDU + kb + c4);
    float4 bv = (kb + r < NHH)
                    ? *(const float4*)(v + (size_t)(kb + r) * SDIM + t0 + c4)
                    : make_float4(0.f, 0.f, 0.f, 0.f);
    *(float4*)&As[r][c4] = av;
    *(float4*)&Bs[r][c4] = bv;
    __syncthreads();
#pragma unroll
    for (int kk = 0; kk < 32; kk++) {
      float a0 = As[ty * 2][kk], a1 = As[ty * 2 + 1][kk];
      float b0 = Bs[kk][tx * 2], b1 = Bs[kk][tx * 2 + 1];
      acc00 = fmaf(a0, b0, acc00);
      acc01 = fmaf(a0, b1, acc01);
      acc10 = fmaf(a1, b0, acc10);
      acc11 = fmaf(a1, b1, acc11);
    }
  }
  int row0 = s0 + ty * 2, col0 = t0 + tx * 2;
  QTT[(size_t)row0 * SDIM + col0] =
      (__fp16)(((row0 == col0) ? 1.f : 0.f) - acc00);
  QTT[(size_t)row0 * SDIM + col0 + 1] =
      (__fp16)(((row0 == col0 + 1) ? 1.f : 0.f) - acc01);
  QTT[(size_t)(row0 + 1) * SDIM + col0] =
      (__fp16)(((row0 + 1 == col0) ? 1.f : 0.f) - acc10);
  QTT[(size_t)(row0 + 1) * SDIM + col0 + 1] =
      (__fp16)(((row0 + 1 == col0 + 1) ? 1.f : 0.f) - acc11);
}

// ---------------- Main GEMM: C[65536x512] = X(f32->f16) @ QTT^T ----------
__global__ __launch_bounds__(256) void gemm_k(const float* __restrict__ X,
                                              const __fp16* __restrict__ BT,
                                              float* __restrict__ C) {
  __shared__ __attribute__((aligned(16))) float As[128 * 32];
  __shared__ __attribute__((aligned(16))) __fp16 Bs[128 * 32];
  const int t = threadIdx.x;
  const int lane = t & 63, wave = t >> 6;
  const int m0 = blockIdx.y * 128, n0 = blockIdx.x * 128;
  const int wm = (wave >> 1) * 64, wn = (wave & 1) * 64;
  const int rr = lane & 15, kg = lane >> 4;
  const int wb = t & ~63;  // wave-uniform thread base

  f32x4 acc[4][4];
#pragma unroll
  for (int a = 0; a < 4; a++)
#pragma unroll
    for (int b = 0; b < 4; b++) acc[a][b] = (f32x4){0.f, 0.f, 0.f, 0.f};

  for (int k0 = 0; k0 < 512; k0 += 32) {
    __syncthreads();
    // A tile: 128x32 f32, 16 KB -> 4 issues of 16B/lane
#pragma unroll
    for (int q = 0; q < 4; q++) {
      int idx = q * 256 + t;
      int r = idx >> 3, c = (idx & 7) * 4;
      const float* gp = X + (size_t)(m0 + r) * 512 + k0 + c;
      gl_lds16(gp, (void*)&As[(size_t)(q * 256 + wb) * 4]);
    }
    // B tile: 128x32 f16, 8 KB -> 2 issues
#pragma unroll
    for (int q = 0; q < 2; q++) {
      int idx = q * 256 + t;
      int r = idx >> 2, c = (idx & 3) * 8;
      const __fp16* gp = BT + (size_t)(n0 + r) * 512 + k0 + c;
      gl_lds16(gp, (void*)&Bs[(size_t)(q * 256 + wb) * 8]);
    }
    asm volatile("s_waitcnt vmcnt(0)" ::: "memory");
    __syncthreads();

    h16x8 af[4], bf[4];
#pragma unroll
    for (int mi = 0; mi < 4; mi++) {
      const float* ap = &As[(size_t)(wm + mi * 16 + rr) * 32 + kg * 8];
      float4 lo = *(const float4*)ap;
      float4 hi = *(const float4*)(ap + 4);
      h16x2 p0 = __builtin_amdgcn_cvt_pkrtz(lo.x, lo.y);
      h16x2 p1 = __builtin_amdgcn_cvt_pkrtz(lo.z, lo.w);
      h16x2 p2 = __builtin_amdgcn_cvt_pkrtz(hi.x, hi.y);
      h16x2 p3 = __builtin_amdgcn_cvt_pkrtz(hi.z, hi.w);
      h16x8 a = {p0[0], p0[1], p1[0], p1[1], p2[0], p2[1], p3[0], p3[1]};
      af[mi] = a;
    }
#pragma unroll
    for (int ni = 0; ni < 4; ni++)
      bf[ni] = *(const h16x8*)&Bs[(size_t)(wn + ni * 16 + rr) * 32 + kg * 8];

#pragma unroll
    for (int mi = 0; mi < 4; mi++)
#pragma unroll
      for (int ni = 0; ni < 4; ni++)
        acc[mi][ni] =
            __builtin_amdgcn_mfma_f32_16x16x32_f16(af[mi], bf[ni], acc[mi][ni], 0, 0, 0);
  }

  // Epilogue via LDS: full-128B-line float4 stores (R2: scalar dword stores
  // correlated with +131 MB FETCH == C-size -> suspected RMW line fills).
  __syncthreads();
  float* Ep = (float*)As;  // 16 KB = 2 bufs x 16 rows x 128 cols
  const int lr = (lane >> 4) * 4;
  const int lc = wn + rr;
  const int buf = wave >> 1;
#pragma unroll
  for (int rnd = 0; rnd < 4; rnd++) {
    float* bp = Ep + buf * 2048;
#pragma unroll
    for (int ni = 0; ni < 4; ni++)
#pragma unroll
      for (int q = 0; q < 4; q++)
        bp[(lr + q) * 128 + lc + ni * 16] = acc[rnd][ni][q];
    __syncthreads();
#pragma unroll
    for (int j = 0; j < 4; j++) {
      int fidx = j * 256 + t;      // 0..1023 float4s
      int b = fidx >> 9;           // which buf (0: rows wm=0, 1: rows wm=64)
      int wi = fidx & 511;
      int lrow = wi >> 5;
      int c4 = wi & 31;
      int grow = m0 + b * 64 + rnd * 16 + lrow;
      *(float4*)(C + (size_t)grow * 512 + n0 + c4 * 4) =
          *(const float4*)(Ep + b * 2048 + lrow * 128 + c4 * 4);
    }
    __syncthreads();
  }
}

extern "C" void kernel_launch(void* const* d_in, const int* in_sizes, int n_in,
                              void* d_out, int out_size, void* d_ws, size_t ws_size,
                              hipStream_t stream) {
  const float* x = (const float*)d_in[0];        // [65536][512] f32
  const float* v = (const float*)d_in[1];        // [514][512] f32
  float* out = (float*)d_out;                    // [65536][512] f32

  char* w = (char*)d_ws;
  float* G = (float*)w;                                   // 528*520*4 = 1,098,240 B
  float* U = (float*)(w + (size_t)GROWS * LDG * 4);       // 512*520*4 = 1,064,960 B
  __fp16* QTT =
      (__fp16*)(w + (size_t)GROWS * LDG * 4 + (size_t)512 * LDU * 4);  // 512 KB

  gram_k<<<dim3(17, 17), 256, 0, stream>>>(v, G);
  solve_k<<<128, 256, 0, stream>>>(v, G, U);
  qtt_k<<<dim3(16, 16), 256, 0, stream>>>(v, U, QTT);
  gemm_k<<<dim3(4, 512), 256, 0, stream>>>(x, QTT, out);
}